// Round 1
// 359.758 us; speedup vs baseline: 1.2158x; 1.2158x over previous
//
#include <hip/hip_runtime.h>

#define WSZ 8
#define NHE 4
#define CH 64

typedef unsigned short u16;
typedef __attribute__((ext_vector_type(8))) short short8;
typedef __attribute__((ext_vector_type(4))) short short4v;
typedef __attribute__((ext_vector_type(4))) float float4v;

__device__ __forceinline__ u16 f2bf(float f) {
    unsigned u = __float_as_uint(f);
    u += 0x7fff + ((u >> 16) & 1);   // round-to-nearest-even
    return (u16)(u >> 16);
}
// XOR swizzle for [row][64] bf16 arrays: keeps 8-elem (16B) chunks intact,
// spreads the 8 chunk slots across banks by row.
__device__ __forceinline__ int SW(int row, int col) {
    return row * 64 + (col ^ ((row & 7) << 3));
}

#define MFMA(a, b, c) __builtin_amdgcn_mfma_f32_16x16x32_bf16(a, b, c, 0, 0, 0)

// ---- pre-kernel (runs once per launch, ~2us): bf16 weights in per-lane
// fragment layout + rpb expanded to a per-(h,mt,q,lane) coalesced bias table.
__global__ void prep(const float* __restrict__ qkvw, const float* __restrict__ projw,
                     const float* __restrict__ rpb,
                     u16* __restrict__ wq, u16* __restrict__ wp, float* __restrict__ bl)
{
    int t = blockIdx.x * 256 + threadIdx.x;   // 64 blocks x 256 = 16384
    if (t < 12288) {  // qkv weights: layout [nt][kt][q][nl][8]
        int j = t & 7, nl = (t >> 3) & 15, q = (t >> 7) & 3, kt = (t >> 9) & 1, nt = t >> 10;
        wq[t] = f2bf(qkvw[(nt * 16 + nl) * CH + kt * 32 + q * 8 + j]);
    }
    if (t < 4096) {   // proj weights: layout [wv][kt][q][nl][8]
        int j = t & 7, nl = (t >> 3) & 15, q = (t >> 7) & 3, kt = (t >> 9) & 1, wv = t >> 10;
        wp[t] = f2bf(projw[(wv * 16 + nl) * CH + kt * 32 + q * 8 + j]);
    }
    if (t < 16384) {  // bias: layout [h][mt][q][nl][r][nt] -> lane reads 64B contiguous
        int nt = t & 3, r = (t >> 2) & 3, nl = (t >> 4) & 15,
            q = (t >> 8) & 3, mt = (t >> 10) & 3, h = t >> 12;
        int tokm = mt * 16 + q * 4 + r, tokn = nt * 16 + nl;
        int im = tokm >> 3, jm = tokm & 7, in_ = tokn >> 3, jn = tokn & 7;
        bl[t] = rpb[((im - in_ + 7) * 15 + (jm - jn + 7)) * NHE + h];
    }
}

// One block per 8x8 window; 4 waves. LDS = 32768 B exactly -> 5 blocks/CU.
// Aliasing (all barrier-separated):
//   [0..16384)   XS fp32 [64ch][64tok] (ph0-1)  ->  QO bf16 (0..8K) + KS bf16 (8K..16K) (ph2+)
//   [16384..24576) XN bf16 [64tok][64ch] swz (ph1-2) -> per-wave P (ph3)
//   [24576..32768) LN scratch PS/PS2/MU/RS (ph1)  ->  VS bf16 [64ch][64tok] (ph2+)
// Residual x is re-read from global in ph4 (same lines as ph0 -> L2-hot).
__global__ __launch_bounds__(256, 5) void win_attn(
    const float* __restrict__ x, const float* __restrict__ nw, const float* __restrict__ nb,
    const u16* __restrict__ wq, const u16* __restrict__ wp,
    const float* __restrict__ ascale, const float* __restrict__ biasl,
    float* __restrict__ out, int B, int H, int W)
{
    const int HWsz = H * W;
    const int nww = W / WSZ, nwh = H / WSZ;
    // XCD-chunked swizzle: nwin = B*1024 is always %8==0; XCD k gets a
    // contiguous win range so horizontally-adjacent windows share L2 lines.
    const int win = (blockIdx.x & 7) * ((int)gridDim.x >> 3) + (blockIdx.x >> 3);
    const int ww = win % nww;
    const int t1 = win / nww;
    const int wh = t1 % nwh;
    const int b  = t1 / nwh;

    const int tid  = threadIdx.x;
    const int lane = tid & 63;
    const int wv   = tid >> 6;
    const int q    = lane >> 4;   // quad
    const int nl   = lane & 15;

    __shared__ alignas(16) char smem[32768];
    float* XS  = (float*)(smem);
    u16*   QO  = (u16*)(smem);
    u16*   KS  = (u16*)(smem + 8192);
    u16*   XN  = (u16*)(smem + 16384);
    u16*   VS  = (u16*)(smem + 24576);
    float* PS  = (float*)(smem + 24576);
    float* PS2 = PS + 256;
    float* MUs = PS + 512;
    float* RSs = PS + 576;

    const int rowbase = (wh * WSZ) * W + ww * WSZ;
    const float* xw = x + (size_t)b * CH * HWsz + rowbase;

    // ---- phase 0: x window -> XS [ch][tok], float4 ----
    for (int e = tid; e < 1024; e += 256) {
        int c = e >> 4, r = e & 15;
        int i = r >> 1, j4 = (r & 1) * 4;
        float4v v = *(const float4v*)(xw + c * HWsz + i * W + j4);
        *(float4v*)&XS[c * 64 + i * 8 + j4] = v;
    }
    __syncthreads();

    // ---- phase 1: LayerNorm over channels (split across waves) ----
    {
        float s = 0.f, s2 = 0.f;
        #pragma unroll
        for (int ci = 0; ci < 16; ci++) {
            float v = XS[(wv * 16 + ci) * 64 + lane];
            s += v; s2 += v * v;
        }
        PS[wv * 64 + lane] = s;
        PS2[wv * 64 + lane] = s2;
    }
    __syncthreads();
    if (tid < 64) {
        float s  = PS[tid]  + PS[64 + tid]  + PS[128 + tid]  + PS[192 + tid];
        float s2 = PS2[tid] + PS2[64 + tid] + PS2[128 + tid] + PS2[192 + tid];
        float mu  = s * (1.f / 64.f);
        float var = s2 * (1.f / 64.f) - mu * mu;
        MUs[tid] = mu;
        RSs[tid] = rsqrtf(var + 1e-5f);
    }
    __syncthreads();
    {
        float mu = MUs[lane], rs = RSs[lane];
        #pragma unroll
        for (int ci = 0; ci < 16; ci++) {
            int c = wv * 16 + ci;                       // wave-uniform -> s_load nw/nb
            float v = (XS[c * 64 + lane] - mu) * rs * nw[c] + nb[c];
            XN[SW(lane, c)] = f2bf(v);
        }
    }
    __syncthreads();

    // ---- phase 2: QKV GEMM (M=64 tok, N=192, K=64), wave w owns n-tiles 3w..3w+2 ----
    {
        // pre-converted bf16 weights, perfectly coalesced 16B/lane loads
        short8 bfrs[3][2];
        #pragma unroll
        for (int nt3 = 0; nt3 < 3; nt3++) {
            int nt = wv * 3 + nt3;
            #pragma unroll
            for (int kt = 0; kt < 2; kt++)
                bfrs[nt3][kt] = *(const short8*)&wq[((((nt * 2 + kt) * 4 + q) * 16) + nl) * 8];
        }
        short8 afr[4][2];
        #pragma unroll
        for (int mt = 0; mt < 4; mt++)
            #pragma unroll
            for (int kt = 0; kt < 2; kt++) {
                int m = mt * 16 + nl;
                int phys = (kt * 4 + q) ^ (m & 7);
                afr[mt][kt] = *(short8*)&XN[m * 64 + phys * 8];
            }
        #pragma unroll
        for (int nt3 = 0; nt3 < 3; nt3++) {
            int nt = wv * 3 + nt3;
            int which = nt >> 2;                 // 0:Q 1:K 2:V (wave-uniform)
            int chb = (nt & 3) * 16 + nl;        // output channel within q/k/v
            #pragma unroll
            for (int mt = 0; mt < 4; mt++) {
                float4v acc = {0.f, 0.f, 0.f, 0.f};
                acc = MFMA(afr[mt][0], bfrs[nt3][0], acc);
                acc = MFMA(afr[mt][1], bfrs[nt3][1], acc);
                int tok0 = mt * 16 + q * 4;
                if (which == 0) {
                    #pragma unroll
                    for (int r = 0; r < 4; r++) QO[SW(tok0 + r, chb)] = f2bf(acc[r]);
                } else if (which == 1) {
                    #pragma unroll
                    for (int r = 0; r < 4; r++) KS[SW(tok0 + r, chb)] = f2bf(acc[r]);
                } else {
                    short4v pk;
                    pk[0] = (short)f2bf(acc[0]); pk[1] = (short)f2bf(acc[1]);
                    pk[2] = (short)f2bf(acc[2]); pk[3] = (short)f2bf(acc[3]);
                    int pt = tok0 ^ ((chb & 7) << 3);    // V is [ch][tok]: 4 toks contiguous
                    *(short4v*)&VS[chb * 64 + pt] = pk;
                }
            }
        }
    }
    __syncthreads();

    // ---- phase 3: attention, wave = head h; K=16 zero-padded to MFMA K=32 ----
    {
        const int h = wv;
        u16* Pw = XN + wv * 1024;   // per-wave P [16][64] bf16 (XN dead)
        const short8 zero8 = {0, 0, 0, 0, 0, 0, 0, 0};
        short8 kfr[4], vfr[2];
        #pragma unroll
        for (int nt = 0; nt < 4; nt++) {
            if (q < 2) {
                int n = nt * 16 + nl;
                int phys = (h * 2 + q) ^ (n & 7);
                kfr[nt] = *(short8*)&KS[n * 64 + phys * 8];
            } else kfr[nt] = zero8;
        }
        #pragma unroll
        for (int kt = 0; kt < 2; kt++) {
            int c = h * 16 + nl;
            int phys = (kt * 4 + q) ^ (c & 7);
            vfr[kt] = *(short8*)&VS[c * 64 + phys * 8];
        }
        #pragma unroll
        for (int mt = 0; mt < 4; mt++) {
            // coalesced bias prefetch: 64B/lane from the precomputed table
            const float4v* bp = (const float4v*)(biasl + ((((h * 4 + mt) * 4 + q) * 16 + nl) << 4));
            float4v blv[4];
            blv[0] = bp[0]; blv[1] = bp[1]; blv[2] = bp[2]; blv[3] = bp[3];
            short8 qf;
            if (q < 2) {
                int m = mt * 16 + nl;
                int phys = (h * 2 + q) ^ (m & 7);
                qf = *(short8*)&QO[m * 64 + phys * 8];
            } else qf = zero8;
            float4v sacc[4];
            #pragma unroll
            for (int nt = 0; nt < 4; nt++) {
                float4v z = {0.f, 0.f, 0.f, 0.f};
                sacc[nt] = MFMA(qf, kfr[nt], z);
            }
            float sv[4][4], mx[4], sum[4], inv[4];
            #pragma unroll
            for (int r = 0; r < 4; r++) mx[r] = -1e30f;
            #pragma unroll
            for (int nt = 0; nt < 4; nt++)
                #pragma unroll
                for (int r = 0; r < 4; r++) {
                    float s = sacc[nt][r] * 0.25f + blv[r][nt];   // hd^-0.5 = 0.25
                    sv[nt][r] = s;
                    mx[r] = fmaxf(mx[r], s);
                }
            #pragma unroll
            for (int r = 0; r < 4; r++) {
                #pragma unroll
                for (int msk = 1; msk <= 8; msk <<= 1)
                    mx[r] = fmaxf(mx[r], __shfl_xor(mx[r], msk, 64));
                sum[r] = 0.f;
            }
            #pragma unroll
            for (int nt = 0; nt < 4; nt++)
                #pragma unroll
                for (int r = 0; r < 4; r++) {
                    float e = __expf(sv[nt][r] - mx[r]);
                    sv[nt][r] = e;
                    sum[r] += e;
                }
            #pragma unroll
            for (int r = 0; r < 4; r++) {
                #pragma unroll
                for (int msk = 1; msk <= 8; msk <<= 1)
                    sum[r] += __shfl_xor(sum[r], msk, 64);
                inv[r] = 1.f / sum[r];
            }
            #pragma unroll
            for (int nt = 0; nt < 4; nt++)
                #pragma unroll
                for (int r = 0; r < 4; r++)
                    Pw[SW(q * 4 + r, nt * 16 + nl)] = f2bf(sv[nt][r] * inv[r]);
            // PV: O[mt] = P[16x64] @ V[64x16]  (per-wave LDS, DS ops in-order per wave)
            float4v oacc = {0.f, 0.f, 0.f, 0.f};
            #pragma unroll
            for (int kt = 0; kt < 2; kt++) {
                int phys = (kt * 4 + q) ^ (nl & 7);
                short8 pf = *(short8*)&Pw[nl * 64 + phys * 8];
                oacc = MFMA(pf, vfr[kt], oacc);
            }
            #pragma unroll
            for (int r = 0; r < 4; r++)
                QO[SW(mt * 16 + q * 4 + r, h * 16 + nl)] = f2bf(oacc[r]);
        }
    }
    __syncthreads();

    // ---- phase 4: proj + residual; wave w owns out-channel tile w ----
    {
        const float asc = ascale[0];
        const int ch = wv * 16 + nl;
        // residual re-read (same lines as phase 0 -> L2-hot); issue early
        const float* xrp = xw + (size_t)ch * HWsz;
        float4v xr[4];
        #pragma unroll
        for (int mt = 0; mt < 4; mt++) {
            int tok0 = mt * 16 + q * 4;
            xr[mt] = *(const float4v*)(xrp + (tok0 >> 3) * W + (tok0 & 7));
        }
        short8 wfr[2];
        #pragma unroll
        for (int kt = 0; kt < 2; kt++)
            wfr[kt] = *(const short8*)&wp[((((wv * 2 + kt) * 4 + q) * 16) + nl) * 8];
        float* outp = out + ((size_t)b * CH + ch) * HWsz + rowbase;
        #pragma unroll
        for (int mt = 0; mt < 4; mt++) {
            float4v yacc = {0.f, 0.f, 0.f, 0.f};
            #pragma unroll
            for (int kt = 0; kt < 2; kt++) {
                int m = mt * 16 + nl;
                int phys = (kt * 4 + q) ^ (m & 7);
                short8 of = *(short8*)&QO[m * 64 + phys * 8];
                yacc = MFMA(of, wfr[kt], yacc);
            }
            int tok0 = mt * 16 + q * 4;                  // 4 consecutive tokens = 4 consecutive j
            int i = tok0 >> 3, j = tok0 & 7;
            float4v y;
            y[0] = xr[mt][0] + asc * yacc[0];
            y[1] = xr[mt][1] + asc * yacc[1];
            y[2] = xr[mt][2] + asc * yacc[2];
            y[3] = xr[mt][3] + asc * yacc[3];
            *(float4v*)(outp + i * W + j) = y;
        }
    }
}

extern "C" void kernel_launch(void* const* d_in, const int* in_sizes, int n_in,
                              void* d_out, int out_size, void* d_ws, size_t ws_size,
                              hipStream_t stream) {
    const float* x     = (const float*)d_in[0];
    const float* nw    = (const float*)d_in[1];
    const float* nb    = (const float*)d_in[2];
    const float* qkvw  = (const float*)d_in[3];
    const float* projw = (const float*)d_in[4];
    const float* asc   = (const float*)d_in[5];
    const float* rpb   = (const float*)d_in[6];

    const int H = 256, W = 256;
    const int B = in_sizes[0] / (CH * H * W);
    const int nwin = B * (H / WSZ) * (W / WSZ);

    // workspace: [0,24576) qkv bf16; [24576,32768) proj bf16; [32768,98304) bias fp32
    u16*   wq = (u16*)d_ws;
    u16*   wp = (u16*)((char*)d_ws + 24576);
    float* bl = (float*)((char*)d_ws + 32768);

    prep<<<64, 256, 0, stream>>>(qkvw, projw, rpb, wq, wp, bl);
    win_attn<<<nwin, 256, 0, stream>>>(x, nw, nb, wq, wp, asc, bl,
                                       (float*)d_out, B, H, W);
}

// Round 3
// 341.160 us; speedup vs baseline: 1.2821x; 1.0545x over previous
//
#include <hip/hip_runtime.h>

#define WSZ 8
#define NHE 4
#define CH 64

typedef unsigned short u16;
typedef __attribute__((ext_vector_type(8))) short short8;
typedef __attribute__((ext_vector_type(4))) short short4v;
typedef __attribute__((ext_vector_type(4))) float float4v;

__device__ __forceinline__ u16 f2bf(float f) {
    unsigned u = __float_as_uint(f);
    u += 0x7fff + ((u >> 16) & 1);   // round-to-nearest-even
    return (u16)(u >> 16);
}
// XOR swizzle for [row][64] bf16 arrays: keeps 8-elem (16B) chunks intact,
// spreads the 8 chunk slots across banks by row.
__device__ __forceinline__ int SW(int row, int col) {
    return row * 64 + (col ^ ((row & 7) << 3));
}

#define MFMA(a, b, c) __builtin_amdgcn_mfma_f32_16x16x32_bf16(a, b, c, 0, 0, 0)

// ---- pre-kernel: bf16 weights in per-lane fragment layout + rpb expanded to
// a coalesced bias table matching the TRANSPOSED-S lane mapping:
//   idx = ((h*4+mt)*64 + lane)*16 + nt*4 + r,
//   query tokm = mt*16 + (lane&15), key tokn = nt*16 + (lane>>4)*4 + r
__global__ void prep(const float* __restrict__ qkvw, const float* __restrict__ projw,
                     const float* __restrict__ rpb,
                     u16* __restrict__ wq, u16* __restrict__ wp, float* __restrict__ bl)
{
    int t = blockIdx.x * 256 + threadIdx.x;   // 64 blocks x 256 = 16384
    if (t < 12288) {  // qkv weights: layout [nt][kt][q][nl][8]
        int j = t & 7, nl = (t >> 3) & 15, q = (t >> 7) & 3, kt = (t >> 9) & 1, nt = t >> 10;
        wq[t] = f2bf(qkvw[(nt * 16 + nl) * CH + kt * 32 + q * 8 + j]);
    }
    if (t < 4096) {   // proj weights: layout [wv][kt][q][nl][8]
        int j = t & 7, nl = (t >> 3) & 15, q = (t >> 7) & 3, kt = (t >> 9) & 1, wv = t >> 10;
        wp[t] = f2bf(projw[(wv * 16 + nl) * CH + kt * 32 + q * 8 + j]);
    }
    if (t < 16384) {  // bias table for transposed-S softmax
        int r = t & 3, nt = (t >> 2) & 3, lane = (t >> 4) & 63, mt = (t >> 10) & 3, h = t >> 12;
        int nl = lane & 15, q = lane >> 4;
        int tokm = mt * 16 + nl, tokn = nt * 16 + q * 4 + r;
        int im = tokm >> 3, jm = tokm & 7, in_ = tokn >> 3, jn = tokn & 7;
        bl[t] = rpb[((im - in_ + 7) * 15 + (jm - jn + 7)) * NHE + h];
    }
}

// One block per 8x8 window; 4 waves. LDS = 32768 B exactly -> 5 blocks/CU.
// Aliasing (all barrier-separated):
//   [0..16384)   XS fp32 [64ch][64tok] (ph0-1)  ->  QO bf16 (0..8K) + KS bf16 (8K..16K) (ph2+)
//   [16384..24576) XN bf16 [64tok][64ch] swz (ph1-2) -> per-wave P (ph3)
//   [24576..32768) LN scratch PS/PS2/MU/RS (ph1)  ->  VS bf16 [64ch][64tok] (ph2+)
// Residual x is re-read from global in ph4 (same lines as ph0 -> L2-hot).
__global__ __launch_bounds__(256, 5) void win_attn(
    const float* __restrict__ x, const float* __restrict__ nw, const float* __restrict__ nb,
    const u16* __restrict__ wq, const u16* __restrict__ wp,
    const float* __restrict__ ascale, const float* __restrict__ biasl,
    float* __restrict__ out, int B, int H, int W)
{
    const int HWsz = H * W;
    const int nww = W / WSZ, nwh = H / WSZ;
    // XCD-chunked swizzle: nwin = B*1024 is always %8==0; XCD k gets a
    // contiguous win range so horizontally-adjacent windows share L2 lines.
    const int win = (blockIdx.x & 7) * ((int)gridDim.x >> 3) + (blockIdx.x >> 3);
    const int ww = win % nww;
    const int t1 = win / nww;
    const int wh = t1 % nwh;
    const int b  = t1 / nwh;

    const int tid  = threadIdx.x;
    const int lane = tid & 63;
    const int wv   = tid >> 6;
    const int q    = lane >> 4;   // quad
    const int nl   = lane & 15;

    __shared__ alignas(16) char smem[32768];
    float* XS  = (float*)(smem);
    u16*   QO  = (u16*)(smem);
    u16*   KS  = (u16*)(smem + 8192);
    u16*   XN  = (u16*)(smem + 16384);
    u16*   VS  = (u16*)(smem + 24576);
    float* PS  = (float*)(smem + 24576);
    float* PS2 = PS + 256;
    float* MUs = PS + 512;
    float* RSs = PS + 576;

    const int rowbase = (wh * WSZ) * W + ww * WSZ;
    const float* xw = x + (size_t)b * CH * HWsz + rowbase;

    // ---- phase 0: x window -> XS [ch][tok], float4 ----
    for (int e = tid; e < 1024; e += 256) {
        int c = e >> 4, r = e & 15;
        int i = r >> 1, j4 = (r & 1) * 4;
        float4v v = *(const float4v*)(xw + c * HWsz + i * W + j4);
        *(float4v*)&XS[c * 64 + i * 8 + j4] = v;
    }
    __syncthreads();

    // ---- phase 1: LayerNorm over channels (split across waves) ----
    {
        float s = 0.f, s2 = 0.f;
        #pragma unroll
        for (int ci = 0; ci < 16; ci++) {
            float v = XS[(wv * 16 + ci) * 64 + lane];
            s += v; s2 += v * v;
        }
        PS[wv * 64 + lane] = s;
        PS2[wv * 64 + lane] = s2;
    }
    __syncthreads();
    if (tid < 64) {
        float s  = PS[tid]  + PS[64 + tid]  + PS[128 + tid]  + PS[192 + tid];
        float s2 = PS2[tid] + PS2[64 + tid] + PS2[128 + tid] + PS2[192 + tid];
        float mu  = s * (1.f / 64.f);
        float var = s2 * (1.f / 64.f) - mu * mu;
        MUs[tid] = mu;
        RSs[tid] = rsqrtf(var + 1e-5f);
    }
    __syncthreads();
    {
        float mu = MUs[lane], rs = RSs[lane];
        #pragma unroll
        for (int ci = 0; ci < 16; ci++) {
            int c = wv * 16 + ci;                       // wave-uniform -> s_load nw/nb
            float v = (XS[c * 64 + lane] - mu) * rs * nw[c] + nb[c];
            XN[SW(lane, c)] = f2bf(v);
        }
    }
    __syncthreads();

    // ---- phase 2: QKV GEMM (M=64 tok, N=192, K=64), wave w owns n-tiles 3w..3w+2 ----
    {
        // pre-converted bf16 weights, perfectly coalesced 16B/lane loads
        short8 bfrs[3][2];
        #pragma unroll
        for (int nt3 = 0; nt3 < 3; nt3++) {
            int nt = wv * 3 + nt3;
            #pragma unroll
            for (int kt = 0; kt < 2; kt++)
                bfrs[nt3][kt] = *(const short8*)&wq[((((nt * 2 + kt) * 4 + q) * 16) + nl) * 8];
        }
        short8 afr[4][2];
        #pragma unroll
        for (int mt = 0; mt < 4; mt++)
            #pragma unroll
            for (int kt = 0; kt < 2; kt++) {
                int m = mt * 16 + nl;
                int phys = (kt * 4 + q) ^ (m & 7);
                afr[mt][kt] = *(short8*)&XN[m * 64 + phys * 8];
            }
        #pragma unroll
        for (int nt3 = 0; nt3 < 3; nt3++) {
            int nt = wv * 3 + nt3;
            int which = nt >> 2;                 // 0:Q 1:K 2:V (wave-uniform)
            int chb = (nt & 3) * 16 + nl;        // output channel within q/k/v
            #pragma unroll
            for (int mt = 0; mt < 4; mt++) {
                float4v acc = {0.f, 0.f, 0.f, 0.f};
                acc = MFMA(afr[mt][0], bfrs[nt3][0], acc);
                acc = MFMA(afr[mt][1], bfrs[nt3][1], acc);
                int tok0 = mt * 16 + q * 4;
                if (which == 0) {
                    #pragma unroll
                    for (int r = 0; r < 4; r++) QO[SW(tok0 + r, chb)] = f2bf(acc[r]);
                } else if (which == 1) {
                    #pragma unroll
                    for (int r = 0; r < 4; r++) KS[SW(tok0 + r, chb)] = f2bf(acc[r]);
                } else {
                    short4v pk;
                    pk[0] = (short)f2bf(acc[0]); pk[1] = (short)f2bf(acc[1]);
                    pk[2] = (short)f2bf(acc[2]); pk[3] = (short)f2bf(acc[3]);
                    int pt = tok0 ^ ((chb & 7) << 3);    // V is [ch][tok]: 4 toks contiguous
                    *(short4v*)&VS[chb * 64 + pt] = pk;
                }
            }
        }
    }
    __syncthreads();

    // ---- phase 3: attention, wave = head h; K=16 zero-padded to MFMA K=32 ----
    // S^T trick: MFMA(kfr, qf) -> lane (nl,q) reg r holds
    // S[query = mt*16+nl][key = nt*16+q*4+r]: a full score row lives in the
    // 4 lanes sharing nl -> softmax = 15 local ops + 2 shuffles (xor 16,32).
    {
        const int h = wv;
        u16* Pw = XN + wv * 1024;   // per-wave P [16 queries][64 keys] bf16 (XN dead)
        const short8 zero8 = {0, 0, 0, 0, 0, 0, 0, 0};
        short8 kfr[4], vfr[2];
        #pragma unroll
        for (int nt = 0; nt < 4; nt++) {
            if (q < 2) {
                int n = nt * 16 + nl;
                int phys = (h * 2 + q) ^ (n & 7);
                kfr[nt] = *(short8*)&KS[n * 64 + phys * 8];
            } else kfr[nt] = zero8;
        }
        #pragma unroll
        for (int kt = 0; kt < 2; kt++) {
            int c = h * 16 + nl;
            int phys = (kt * 4 + q) ^ (c & 7);
            vfr[kt] = *(short8*)&VS[c * 64 + phys * 8];
        }
        #pragma unroll
        for (int mt = 0; mt < 4; mt++) {
            short8 qf;
            if (q < 2) {
                int m = mt * 16 + nl;
                int phys = (h * 2 + q) ^ (m & 7);
                qf = *(short8*)&QO[m * 64 + phys * 8];
            } else qf = zero8;
            // coalesced bias: 64B/lane from the transposed-mapping table
            const float4v* bp = (const float4v*)(biasl + ((((h * 4 + mt) * 64) + lane) << 4));
            float4v sacc[4];
            #pragma unroll
            for (int nt = 0; nt < 4; nt++) {
                float4v z = {0.f, 0.f, 0.f, 0.f};
                sacc[nt] = MFMA(kfr[nt], qf, z);   // transposed S
            }
            float p[16], mx = -1e30f;
            #pragma unroll
            for (int nt = 0; nt < 4; nt++) {
                float4v blv = bp[nt];
                #pragma unroll
                for (int r = 0; r < 4; r++) {
                    float s = sacc[nt][r] * 0.25f + blv[r];   // hd^-0.5 = 0.25
                    p[nt * 4 + r] = s;
                    mx = fmaxf(mx, s);
                }
            }
            mx = fmaxf(mx, __shfl_xor(mx, 16, 64));
            mx = fmaxf(mx, __shfl_xor(mx, 32, 64));
            float sum = 0.f;
            #pragma unroll
            for (int i = 0; i < 16; i++) {
                float e = __expf(p[i] - mx);
                p[i] = e;
                sum += e;
            }
            sum += __shfl_xor(sum, 16, 64);
            sum += __shfl_xor(sum, 32, 64);
            float inv = 1.f / sum;
            #pragma unroll
            for (int nt = 0; nt < 4; nt++)
                #pragma unroll
                for (int r = 0; r < 4; r++)
                    Pw[SW(nl, nt * 16 + q * 4 + r)] = f2bf(p[nt * 4 + r] * inv);
            // PV: O[mt] = P[16x64] @ V[64x16]  (per-wave LDS, DS ops in-order per wave)
            float4v oacc = {0.f, 0.f, 0.f, 0.f};
            #pragma unroll
            for (int kt = 0; kt < 2; kt++) {
                int phys = (kt * 4 + q) ^ (nl & 7);
                short8 pf = *(short8*)&Pw[nl * 64 + phys * 8];
                oacc = MFMA(pf, vfr[kt], oacc);
            }
            #pragma unroll
            for (int r = 0; r < 4; r++)
                QO[SW(mt * 16 + q * 4 + r, h * 16 + nl)] = f2bf(oacc[r]);
        }
    }
    __syncthreads();

    // ---- phase 4: proj + residual; wave w owns out-channel tile w ----
    {
        const float asc = ascale[0];
        const int ch = wv * 16 + nl;
        // residual re-read (same lines as phase 0 -> L2-hot); issue early
        const float* xrp = xw + (size_t)ch * HWsz;
        float4v xr[4];
        #pragma unroll
        for (int mt = 0; mt < 4; mt++) {
            int tok0 = mt * 16 + q * 4;
            xr[mt] = *(const float4v*)(xrp + (tok0 >> 3) * W + (tok0 & 7));
        }
        short8 wfr[2];
        #pragma unroll
        for (int kt = 0; kt < 2; kt++)
            wfr[kt] = *(const short8*)&wp[((((wv * 2 + kt) * 4 + q) * 16) + nl) * 8];
        float* outp = out + ((size_t)b * CH + ch) * HWsz + rowbase;
        #pragma unroll
        for (int mt = 0; mt < 4; mt++) {
            float4v yacc = {0.f, 0.f, 0.f, 0.f};
            #pragma unroll
            for (int kt = 0; kt < 2; kt++) {
                int m = mt * 16 + nl;
                int phys = (kt * 4 + q) ^ (m & 7);
                short8 of = *(short8*)&QO[m * 64 + phys * 8];
                yacc = MFMA(of, wfr[kt], yacc);
            }
            int tok0 = mt * 16 + q * 4;                  // 4 consecutive tokens = 4 consecutive j
            int i = tok0 >> 3, j = tok0 & 7;
            float4v y;
            y[0] = xr[mt][0] + asc * yacc[0];
            y[1] = xr[mt][1] + asc * yacc[1];
            y[2] = xr[mt][2] + asc * yacc[2];
            y[3] = xr[mt][3] + asc * yacc[3];
            *(float4v*)(outp + i * W + j) = y;
        }
    }
}

extern "C" void kernel_launch(void* const* d_in, const int* in_sizes, int n_in,
                              void* d_out, int out_size, void* d_ws, size_t ws_size,
                              hipStream_t stream) {
    const float* x     = (const float*)d_in[0];
    const float* nw    = (const float*)d_in[1];
    const float* nb    = (const float*)d_in[2];
    const float* qkvw  = (const float*)d_in[3];
    const float* projw = (const float*)d_in[4];
    const float* asc   = (const float*)d_in[5];
    const float* rpb   = (const float*)d_in[6];

    const int H = 256, W = 256;
    const int B = in_sizes[0] / (CH * H * W);
    const int nwin = B * (H / WSZ) * (W / WSZ);

    // workspace: [0,24576) qkv bf16; [24576,32768) proj bf16; [32768,98304) bias fp32
    u16*   wq = (u16*)d_ws;
    u16*   wp = (u16*)((char*)d_ws + 24576);
    float* bl = (float*)((char*)d_ws + 32768);

    prep<<<64, 256, 0, stream>>>(qkvw, projw, rpb, wq, wp, bl);
    win_attn<<<nwin, 256, 0, stream>>>(x, nw, nb, wq, wp, asc, bl,
                                       (float*)d_out, B, H, W);
}

// Round 5
// 340.479 us; speedup vs baseline: 1.2846x; 1.0020x over previous
//
#include <hip/hip_runtime.h>
#include <hip/hip_bf16.h>

#define WSZ 8
#define NHE 4
#define CH 64

typedef unsigned short u16;
typedef unsigned int u32;
typedef __attribute__((ext_vector_type(8))) short short8;
typedef __attribute__((ext_vector_type(4))) short short4v;
typedef __attribute__((ext_vector_type(4))) float float4v;

// Native bf16 conversion (RNE). Compiler packs pairs into v_cvt_pk_bf16_f32
// (learn_hip m240: scalar casts beat hand-written cvt_pk asm).
__device__ __forceinline__ u16 f2bf(float f) {
    __hip_bfloat16 h = __float2bfloat16(f);
    return __builtin_bit_cast(u16, h);
}
// XOR swizzle for [row][64] bf16 arrays: keeps 8-elem (16B) chunks intact,
// spreads the 8 chunk slots across banks by row.
__device__ __forceinline__ int SW(int row, int col) {
    return row * 64 + (col ^ ((row & 7) << 3));
}

#define MFMA(a, b, c) __builtin_amdgcn_mfma_f32_16x16x32_bf16(a, b, c, 0, 0, 0)
#define QKSC 0.36067376022224085f   /* 0.25 * log2(e) */

// ---- pre-kernel: bf16 weights in per-lane fragment layout + rpb expanded to
// a coalesced bias table matching the TRANSPOSED-S lane mapping (layout
// verified in R3), PRE-SCALED by log2(e) for the exp2-domain softmax:
//   idx = ((h*4+mt)*64 + lane)*16 + nt*4 + r,
//   query tokm = mt*16 + (lane&15), key tokn = nt*16 + (lane>>4)*4 + r
__global__ void prep(const float* __restrict__ qkvw, const float* __restrict__ projw,
                     const float* __restrict__ rpb,
                     u16* __restrict__ wq, u16* __restrict__ wp, float* __restrict__ bl)
{
    int t = blockIdx.x * 256 + threadIdx.x;   // 64 blocks x 256 = 16384
    if (t < 12288) {  // qkv weights: layout [nt][kt][q][nl][8]
        int j = t & 7, nl = (t >> 3) & 15, q = (t >> 7) & 3, kt = (t >> 9) & 1, nt = t >> 10;
        wq[t] = f2bf(qkvw[(nt * 16 + nl) * CH + kt * 32 + q * 8 + j]);
    }
    if (t < 4096) {   // proj weights: layout [wv][kt][q][nl][8]
        int j = t & 7, nl = (t >> 3) & 15, q = (t >> 7) & 3, kt = (t >> 9) & 1, wv = t >> 10;
        wp[t] = f2bf(projw[(wv * 16 + nl) * CH + kt * 32 + q * 8 + j]);
    }
    if (t < 16384) {  // bias table for transposed-S softmax (log2-domain)
        int r = t & 3, nt = (t >> 2) & 3, lane = (t >> 4) & 63, mt = (t >> 10) & 3, h = t >> 12;
        int nl = lane & 15, q = lane >> 4;
        int tokm = mt * 16 + nl, tokn = nt * 16 + q * 4 + r;
        int im = tokm >> 3, jm = tokm & 7, in_ = tokn >> 3, jn = tokn & 7;
        bl[t] = rpb[((im - in_ + 7) * 15 + (jm - jn + 7)) * NHE + h] * 1.44269504088896341f;
    }
}

// One block per 8x8 window; 4 waves. LDS = 32768 B exactly -> 5 blocks/CU.
// Aliasing (all barrier-separated):
//   [0..16384)   XS fp32 [64ch][64tok] (ph0-1)  ->  QO bf16 (0..8K) + KS bf16 (8K..16K) (ph2+)
//   [16384..24576) XN bf16 [64tok][64ch] swz (ph1-2) -> per-wave P (ph3)
//   [24576..32768) LN scratch PS/PS2 (ph1)  ->  VS bf16 [64ch][64tok] (ph2+)
// Residual x is re-read from global in ph4 (same lines as ph0 -> L2-hot).
__global__ __launch_bounds__(256, 5) void win_attn(
    const float* __restrict__ x, const float* __restrict__ nw, const float* __restrict__ nb,
    const u16* __restrict__ wq, const u16* __restrict__ wp,
    const float* __restrict__ ascale, const float* __restrict__ biasl,
    float* __restrict__ out, int B, int H, int W)
{
    const int HWsz = H * W;
    const int nww = W / WSZ, nwh = H / WSZ;
    // XCD-chunked swizzle: nwin = B*1024 is always %8==0; XCD k gets a
    // contiguous win range so horizontally-adjacent windows share L2 lines.
    const int win = (blockIdx.x & 7) * ((int)gridDim.x >> 3) + (blockIdx.x >> 3);
    const int ww = win % nww;
    const int t1 = win / nww;
    const int wh = t1 % nwh;
    const int b  = t1 / nwh;

    const int tid  = threadIdx.x;
    const int lane = tid & 63;
    const int wv   = tid >> 6;
    const int q    = lane >> 4;   // quad
    const int nl   = lane & 15;

    __shared__ alignas(16) char smem[32768];
    float* XS  = (float*)(smem);
    u16*   QO  = (u16*)(smem);
    u16*   KS  = (u16*)(smem + 8192);
    u16*   XN  = (u16*)(smem + 16384);
    u16*   VS  = (u16*)(smem + 24576);
    float* PS  = (float*)(smem + 24576);
    float* PS2 = PS + 256;

    const int rowbase = (wh * WSZ) * W + ww * WSZ;
    const float* xw = x + (size_t)b * CH * HWsz + rowbase;

    // ---- phase 0: x window -> XS [ch][tok], float4 ----
    for (int e = tid; e < 1024; e += 256) {
        int c = e >> 4, r = e & 15;
        int i = r >> 1, j4 = (r & 1) * 4;
        float4v v = *(const float4v*)(xw + c * HWsz + i * W + j4);
        *(float4v*)&XS[c * 64 + i * 8 + j4] = v;
    }
    __syncthreads();

    // ---- phase 1: LayerNorm over channels (split across waves) ----
    {
        float s = 0.f, s2 = 0.f;
        #pragma unroll
        for (int ci = 0; ci < 16; ci++) {
            float v = XS[(wv * 16 + ci) * 64 + lane];
            s += v; s2 += v * v;
        }
        PS[wv * 64 + lane] = s;
        PS2[wv * 64 + lane] = s2;
    }
    __syncthreads();
    {
        // per-lane finalize (no tid<64 serial step, one barrier fewer)
        float s  = PS[lane]  + PS[64 + lane]  + PS[128 + lane]  + PS[192 + lane];
        float s2 = PS2[lane] + PS2[64 + lane] + PS2[128 + lane] + PS2[192 + lane];
        float mu  = s * (1.f / 64.f);
        float var = s2 * (1.f / 64.f) - mu * mu;
        float rs  = rsqrtf(var + 1e-5f);
        #pragma unroll
        for (int ci = 0; ci < 16; ci++) {
            int c = wv * 16 + ci;                       // wave-uniform -> s_load nw/nb
            float v = (XS[c * 64 + lane] - mu) * rs * nw[c] + nb[c];
            XN[SW(lane, c)] = f2bf(v);
        }
    }
    __syncthreads();

    // ---- phase 2: QKV GEMM (M=64 tok, N=192, K=64), wave w owns n-tiles 3w..3w+2 ----
    {
        // pre-converted bf16 weights, perfectly coalesced 16B/lane loads
        short8 bfrs[3][2];
        #pragma unroll
        for (int nt3 = 0; nt3 < 3; nt3++) {
            int nt = wv * 3 + nt3;
            #pragma unroll
            for (int kt = 0; kt < 2; kt++)
                bfrs[nt3][kt] = *(const short8*)&wq[((((nt * 2 + kt) * 4 + q) * 16) + nl) * 8];
        }
        short8 afr[4][2];
        #pragma unroll
        for (int mt = 0; mt < 4; mt++)
            #pragma unroll
            for (int kt = 0; kt < 2; kt++) {
                int m = mt * 16 + nl;
                int phys = (kt * 4 + q) ^ (m & 7);
                afr[mt][kt] = *(short8*)&XN[m * 64 + phys * 8];
            }
        #pragma unroll
        for (int nt3 = 0; nt3 < 3; nt3++) {
            int nt = wv * 3 + nt3;
            int which = nt >> 2;                 // 0:Q 1:K 2:V (wave-uniform)
            int chb = (nt & 3) * 16 + nl;        // output channel within q/k/v
            #pragma unroll
            for (int mt = 0; mt < 4; mt++) {
                float4v acc = {0.f, 0.f, 0.f, 0.f};
                acc = MFMA(afr[mt][0], bfrs[nt3][0], acc);
                acc = MFMA(afr[mt][1], bfrs[nt3][1], acc);
                int tok0 = mt * 16 + q * 4;
                if (which == 0) {
                    #pragma unroll
                    for (int r = 0; r < 4; r++) QO[SW(tok0 + r, chb)] = f2bf(acc[r]);
                } else if (which == 1) {
                    #pragma unroll
                    for (int r = 0; r < 4; r++) KS[SW(tok0 + r, chb)] = f2bf(acc[r]);
                } else {
                    short4v pk;
                    pk[0] = (short)f2bf(acc[0]); pk[1] = (short)f2bf(acc[1]);
                    pk[2] = (short)f2bf(acc[2]); pk[3] = (short)f2bf(acc[3]);
                    int pt = tok0 ^ ((chb & 7) << 3);    // V is [ch][tok]: 4 toks contiguous
                    *(short4v*)&VS[chb * 64 + pt] = pk;
                }
            }
        }
    }
    __syncthreads();

    // ---- phase 3: attention, wave = head h; K=16 zero-padded to MFMA K=32 ----
    // S^T trick: MFMA(kfr, qf) -> lane (nl,q) reg r holds
    // S[query = mt*16+nl][key = nt*16+q*4+r]: a full score row lives in the
    // 4 lanes sharing nl -> softmax = 15 local ops + 2 shuffles (xor 16,32).
    {
        const int h = wv;
        u16* Pw = XN + wv * 1024;   // per-wave P [16 queries][64 keys] bf16 (XN dead)
        const short8 zero8 = {0, 0, 0, 0, 0, 0, 0, 0};
        short8 kfr[4], vfr[2];
        #pragma unroll
        for (int nt = 0; nt < 4; nt++) {
            if (q < 2) {
                int n = nt * 16 + nl;
                int phys = (h * 2 + q) ^ (n & 7);
                kfr[nt] = *(short8*)&KS[n * 64 + phys * 8];
            } else kfr[nt] = zero8;
        }
        #pragma unroll
        for (int kt = 0; kt < 2; kt++) {
            int c = h * 16 + nl;
            int phys = (kt * 4 + q) ^ (c & 7);
            vfr[kt] = *(short8*)&VS[c * 64 + phys * 8];
        }
        #pragma unroll
        for (int mt = 0; mt < 4; mt++) {
            short8 qf;
            if (q < 2) {
                int m = mt * 16 + nl;
                int phys = (h * 2 + q) ^ (m & 7);
                qf = *(short8*)&QO[m * 64 + phys * 8];
            } else qf = zero8;
            // coalesced bias: 64B/lane from the transposed-mapping table (log2-domain)
            const float4v* bp = (const float4v*)(biasl + ((((h * 4 + mt) * 64) + lane) << 4));
            float4v sacc[4];
            #pragma unroll
            for (int nt = 0; nt < 4; nt++) {
                float4v z = {0.f, 0.f, 0.f, 0.f};
                sacc[nt] = MFMA(kfr[nt], qf, z);   // transposed S
            }
            float p[16], mx = -1e30f;
            #pragma unroll
            for (int nt = 0; nt < 4; nt++) {
                float4v blv = bp[nt];
                #pragma unroll
                for (int r = 0; r < 4; r++) {
                    float s = fmaf(sacc[nt][r], QKSC, blv[r]);   // log2-domain score
                    p[nt * 4 + r] = s;
                    mx = fmaxf(mx, s);
                }
            }
            mx = fmaxf(mx, __shfl_xor(mx, 16, 64));
            mx = fmaxf(mx, __shfl_xor(mx, 32, 64));
            float sum = 0.f;
            #pragma unroll
            for (int i = 0; i < 16; i++) {
                float e = __builtin_amdgcn_exp2f(p[i] - mx);
                p[i] = e;
                sum += e;
            }
            sum += __shfl_xor(sum, 16, 64);
            sum += __shfl_xor(sum, 32, 64);
            float inv = __builtin_amdgcn_rcpf(sum);
            #pragma unroll
            for (int nt = 0; nt < 4; nt++)
                #pragma unroll
                for (int r = 0; r < 4; r++)
                    Pw[SW(nl, nt * 16 + q * 4 + r)] = f2bf(p[nt * 4 + r] * inv);
            // PV: O[mt] = P[16x64] @ V[64x16]  (per-wave LDS, DS ops in-order per wave)
            float4v oacc = {0.f, 0.f, 0.f, 0.f};
            #pragma unroll
            for (int kt = 0; kt < 2; kt++) {
                int phys = (kt * 4 + q) ^ (nl & 7);
                short8 pf = *(short8*)&Pw[nl * 64 + phys * 8];
                oacc = MFMA(pf, vfr[kt], oacc);
            }
            #pragma unroll
            for (int r = 0; r < 4; r++)
                QO[SW(mt * 16 + q * 4 + r, h * 16 + nl)] = f2bf(oacc[r]);
        }
    }
    __syncthreads();

    // ---- phase 4: proj + residual; wave w owns out-channel tile w ----
    {
        const float asc = ascale[0];
        const int ch = wv * 16 + nl;
        // residual re-read (same lines as phase 0 -> L2-hot); issue early
        const float* xrp = xw + (size_t)ch * HWsz;
        float4v xr[4];
        #pragma unroll
        for (int mt = 0; mt < 4; mt++) {
            int tok0 = mt * 16 + q * 4;
            xr[mt] = *(const float4v*)(xrp + (tok0 >> 3) * W + (tok0 & 7));
        }
        short8 wfr[2];
        #pragma unroll
        for (int kt = 0; kt < 2; kt++)
            wfr[kt] = *(const short8*)&wp[((((wv * 2 + kt) * 4 + q) * 16) + nl) * 8];
        float* outp = out + ((size_t)b * CH + ch) * HWsz + rowbase;
        #pragma unroll
        for (int mt = 0; mt < 4; mt++) {
            float4v yacc = {0.f, 0.f, 0.f, 0.f};
            #pragma unroll
            for (int kt = 0; kt < 2; kt++) {
                int m = mt * 16 + nl;
                int phys = (kt * 4 + q) ^ (m & 7);
                short8 of = *(short8*)&QO[m * 64 + phys * 8];
                yacc = MFMA(of, wfr[kt], yacc);
            }
            int tok0 = mt * 16 + q * 4;                  // 4 consecutive tokens = 4 consecutive j
            int i = tok0 >> 3, j = tok0 & 7;
            float4v y;
            y[0] = xr[mt][0] + asc * yacc[0];
            y[1] = xr[mt][1] + asc * yacc[1];
            y[2] = xr[mt][2] + asc * yacc[2];
            y[3] = xr[mt][3] + asc * yacc[3];
            *(float4v*)(outp + i * W + j) = y;
        }
    }
}

extern "C" void kernel_launch(void* const* d_in, const int* in_sizes, int n_in,
                              void* d_out, int out_size, void* d_ws, size_t ws_size,
                              hipStream_t stream) {
    const float* x     = (const float*)d_in[0];
    const float* nw    = (const float*)d_in[1];
    const float* nb    = (const float*)d_in[2];
    const float* qkvw  = (const float*)d_in[3];
    const float* projw = (const float*)d_in[4];
    const float* asc   = (const float*)d_in[5];
    const float* rpb   = (const float*)d_in[6];

    const int H = 256, W = 256;
    const int B = in_sizes[0] / (CH * H * W);
    const int nwin = B * (H / WSZ) * (W / WSZ);

    // workspace: [0,24576) qkv bf16; [24576,32768) proj bf16; [32768,98304) bias fp32
    u16*   wq = (u16*)d_ws;
    u16*   wp = (u16*)((char*)d_ws + 24576);
    float* bl = (float*)((char*)d_ws + 32768);

    prep<<<64, 256, 0, stream>>>(qkvw, projw, rpb, wq, wp, bl);
    win_attn<<<nwin, 256, 0, stream>>>(x, nw, nb, wq, wp, asc, bl,
                                       (float*)d_out, B, H, W);
}